// Round 2
// baseline (308.476 us; speedup 1.0000x reference)
//
#include <hip/hip_runtime.h>

typedef __bf16 bf16;
typedef __attribute__((ext_vector_type(4))) __bf16 bf16x4;
typedef __attribute__((ext_vector_type(8))) __bf16 bf16x8;
typedef __attribute__((ext_vector_type(4))) float f32x4;
typedef __attribute__((ext_vector_type(4))) unsigned int u32x4;

#define B_ 4
#define S_ 2048
#define D_ 1024
#define H_ 16
#define HD_ 64

#define GLB(p) ((const __attribute__((address_space(1))) void*)(p))
#define LDS(p) ((__attribute__((address_space(3))) void*)(p))

// ---------------- pass 0a: weight transpose+convert (K,N)fp32 -> (N,K)bf16 --
__global__ __launch_bounds__(256) void transpose_cvt(
    const float* __restrict__ W0, const float* __restrict__ W1,
    const float* __restrict__ W2, const float* __restrict__ W3,
    bf16* __restrict__ T0, bf16* __restrict__ T1,
    bf16* __restrict__ T2, bf16* __restrict__ T3)
{
    __shared__ float tile[32][33];
    int z = blockIdx.z;
    const float* W = (z == 0) ? W0 : (z == 1) ? W1 : (z == 2) ? W2 : W3;
    bf16*        T = (z == 0) ? T0 : (z == 1) ? T1 : (z == 2) ? T2 : T3;
    int bx = blockIdx.x * 32, by = blockIdx.y * 32;
    int tx = threadIdx.x & 31, ty = threadIdx.x >> 5;
    #pragma unroll
    for (int j = 0; j < 32; j += 8)
        tile[ty + j][tx] = W[(size_t)(by + ty + j) * D_ + bx + tx];
    __syncthreads();
    #pragma unroll
    for (int j = 0; j < 32; j += 8)
        T[(size_t)(bx + ty + j) * D_ + by + tx] = (bf16)tile[tx][ty + j];
}

// ---------------- pass 0b: X fp32 -> bf16 ----------------
__global__ __launch_bounds__(256) void cvt_x(
    const float* __restrict__ X, bf16* __restrict__ Xb)
{
    size_t i = ((size_t)blockIdx.x * 256 + threadIdx.x) * 8;
    f32x4 a = *(const f32x4*)(X + i);
    f32x4 b = *(const f32x4*)(X + i + 4);
    bf16x8 v;
    #pragma unroll
    for (int j = 0; j < 4; ++j) { v[j] = (bf16)a[j]; v[4 + j] = (bf16)b[j]; }
    *(bf16x8*)(Xb + i) = v;
}

// ---------------- pass 1: fused QKV projection GEMM ----------------
// C(8192x1024) = Xb(bf16) @ W, WT(N,K) bf16 in ws. 128x128 tile, BK=32.
// Staging via global_load_lds width=16. Epilogue: Q -> (b,h,s,hd) pre-scaled
// by log2(e)/8; K -> (b,h,s,hd); V -> (b,h,hd,s) transposed (packed stores).
__global__ __launch_bounds__(256) void qkv_gemm(
    const bf16* __restrict__ Xb,
    const bf16* __restrict__ WqT, const bf16* __restrict__ WkT, const bf16* __restrict__ WvT,
    const float* __restrict__ bq, const float* __restrict__ bk, const float* __restrict__ bv,
    bf16* __restrict__ Qo, bf16* __restrict__ Ko, bf16* __restrict__ Vo)
{
    const int z = blockIdx.z;
    const bf16*  WT   = (z == 0) ? WqT : (z == 1) ? WkT : WvT;
    const float* bias = (z == 0) ? bq  : (z == 1) ? bk  : bv;
    bf16*        out  = (z == 0) ? Qo  : (z == 1) ? Ko  : Vo;
    const float scale = (z == 0) ? 0.18033688011112042f : 1.0f;

    __shared__ bf16 As[128 * 32];
    __shared__ bf16 Bs[128 * 32];

    const int t = threadIdx.x;
    const int lid = t & 63, w = t >> 6;
    const int wm = w & 1, wn = w >> 1;
    const int lrow = lid & 15, quad = lid >> 4;
    const int m0 = blockIdx.y * 128, n0 = blockIdx.x * 128;

    const bf16* Ag = Xb + (size_t)m0 * D_;
    const bf16* Bg = WT + (size_t)n0 * D_;

    const int row0 = t >> 2, k80 = (t & 3) << 3;
    const int row1 = (t + 256) >> 2;

    f32x4 acc[4][4] = {};

    for (int k0 = 0; k0 < D_; k0 += 32) {
        __syncthreads();
        __builtin_amdgcn_global_load_lds(GLB(Ag + (size_t)row0 * D_ + k0 + k80),
                                         LDS(As + t * 8), 16, 0, 0);
        __builtin_amdgcn_global_load_lds(GLB(Bg + (size_t)row0 * D_ + k0 + k80),
                                         LDS(Bs + t * 8), 16, 0, 0);
        __builtin_amdgcn_global_load_lds(GLB(Ag + (size_t)row1 * D_ + k0 + k80),
                                         LDS(As + t * 8 + 2048), 16, 0, 0);
        __builtin_amdgcn_global_load_lds(GLB(Bg + (size_t)row1 * D_ + k0 + k80),
                                         LDS(Bs + t * 8 + 2048), 16, 0, 0);
        __syncthreads();
        bf16x8 a[4], b[4];
        #pragma unroll
        for (int mb = 0; mb < 4; ++mb)
            a[mb] = *(const bf16x8*)(As + (wm * 64 + mb * 16 + lrow) * 32 + quad * 8);
        #pragma unroll
        for (int nb = 0; nb < 4; ++nb)
            b[nb] = *(const bf16x8*)(Bs + (wn * 64 + nb * 16 + lrow) * 32 + quad * 8);
        #pragma unroll
        for (int mb = 0; mb < 4; ++mb)
            #pragma unroll
            for (int nb = 0; nb < 4; ++nb)
                acc[mb][nb] = __builtin_amdgcn_mfma_f32_16x16x32_bf16(a[mb], b[nb], acc[mb][nb], 0, 0, 0);
    }

    #pragma unroll
    for (int mb = 0; mb < 4; ++mb) {
        #pragma unroll
        for (int nb = 0; nb < 4; ++nb) {
            int gn = n0 + wn * 64 + nb * 16 + lrow;
            float bsv = bias[gn];
            int h = gn >> 6, hd = gn & 63;
            int gm0 = m0 + wm * 64 + mb * 16 + quad * 4;
            int bb = gm0 >> 11, s0 = gm0 & 2047;
            if (z == 2) {
                // V^T: [b, h, hd, s] — 4 consecutive s, packed 8B store
                bf16x4 pk;
                #pragma unroll
                for (int r = 0; r < 4; ++r)
                    pk[r] = (bf16)(acc[mb][nb][r] + bsv);
                *(bf16x4*)(out + (((size_t)(bb * H_ + h)) * HD_ + hd) * S_ + s0) = pk;
            } else {
                // Q/K: [b, h, s, hd]
                #pragma unroll
                for (int r = 0; r < 4; ++r) {
                    float v = (acc[mb][nb][r] + bsv) * scale;
                    out[(((size_t)(bb * H_ + h)) * S_ + (s0 + r)) * HD_ + hd] = (bf16)v;
                }
            }
        }
    }
}

// ---------------- pass 2: causal flash attention (S-transposed scheme) -----
// v3: v2's pipelined global_load_lds double-buffer + swizzle, but LDS cut
// back to 32 KiB by overlaying P into the DEAD Ks[cur] buffer (Ks[cur] is
// fully consumed by QK^T before P is produced). Requires one extra intra-tile
// barrier (raw s_barrier + lgkmcnt-only wait — vmcnt NOT drained, so the
// next-tile prefetch stays in flight across it, T4 discipline).
// LDS = 2*8K (K) + 2*8K (V) = 32768 -> >=4 blocks/CU again (v2's 40960 cost
// us residency: occupancy 34.5%->25.1%, the v2 regression).
// 64-query tiles (32 qtiles). Block pair (31-bx, bx) -> constant 33 key-tile
// units/block; grid (16,64) = 1024 blocks = 4/CU.
__global__ __launch_bounds__(256) void attn_fwd(
    const bf16* __restrict__ Q, const bf16* __restrict__ K,
    const bf16* __restrict__ Vt, bf16* __restrict__ O)
{
    __shared__ bf16 Ks[2][64 * 64];     // [key][hd], 128B rows, XOR-swizzled; P overlay after QK^T
    __shared__ bf16 Vs[2][64 * 64];     // [hd][key], 128B rows, XOR-swizzled

    const int bh = blockIdx.y;
    const int t = threadIdx.x, lid = t & 63, w = t >> 6;
    const int lrow = lid & 15, quad = lid >> 4;
    const int b = bh >> 4, h = bh & 15;

    // read-side swizzle: physical_byte(row, o) = row*128 + (o ^ ((row&7)<<4))
    const int swz = (lrow & 7) << 4;
    const int rk0 = (quad * 16) ^ swz;          // ks=0 fragment byte offset
    // staging: thread t owns linear LDS chunk t*16 (+4096 for 2nd call);
    // global source pre-swizzled so swizzled reads see correct data.
    const int srow0 = t >> 3, srow1 = srow0 + 32;
    const int sc = (t & 7) << 4;
    const int kso0 = srow0 * 128 + (sc ^ ((srow0 & 7) << 4));
    const int kso1 = srow1 * 128 + (sc ^ ((srow1 & 7) << 4));
    const int vso0 = srow0 * (S_ * 2) + (sc ^ ((srow0 & 7) << 4));
    const int vso1 = srow1 * (S_ * 2) + (sc ^ ((srow1 & 7) << 4));

    #pragma unroll 1
    for (int half = 0; half < 2; ++half) {
        const int qtile = half ? blockIdx.x : (31 - blockIdx.x);
        const int qbase = qtile * 64;

        // Q fragments (B-operand): lane n=query=lrow, k=hd in-lane
        const bf16* Qp = Q + ((size_t)bh * S_ + qbase + w * 16) * HD_;
        bf16x8 qf[2];
        #pragma unroll
        for (int ks = 0; ks < 2; ++ks)
            qf[ks] = *(const bf16x8*)(Qp + lrow * HD_ + ks * 32 + quad * 8);

        f32x4 o_acc[4] = {};              // O^T: [hd-block], col=query
        float m_i = -3.0e4f, l_i = 0.0f;

        const char* kp = (const char*)(K  + (size_t)bh * S_ * HD_);
        const char* vp = (const char*)(Vt + (size_t)bh * HD_ * S_);

        // prologue: stage key-tile 0 into buffer 0
        __builtin_amdgcn_global_load_lds(GLB(kp + kso0), LDS((char*)Ks[0] + t * 16), 16, 0, 0);
        __builtin_amdgcn_global_load_lds(GLB(kp + kso1), LDS((char*)Ks[0] + t * 16 + 4096), 16, 0, 0);
        __builtin_amdgcn_global_load_lds(GLB(vp + vso0), LDS((char*)Vs[0] + t * 16), 16, 0, 0);
        __builtin_amdgcn_global_load_lds(GLB(vp + vso1), LDS((char*)Vs[0] + t * 16 + 4096), 16, 0, 0);
        kp += 64 * HD_ * 2;   // next K tile: +8192 B
        vp += 64 * 2;         // next V^T tile: +128 B
        asm volatile("s_waitcnt vmcnt(0)" ::: "memory");
        __builtin_amdgcn_s_barrier();
        asm volatile("" ::: "memory");

        int cur = 0;
        for (int kt = 0; kt <= qtile; ++kt) {
            // issue next-tile staging FIRST — 4 loads stay in flight across
            // the whole compute phase (incl. the mid-tile barrier)
            if (kt < qtile) {
                char* kd = (char*)Ks[cur ^ 1] + t * 16;
                char* vd = (char*)Vs[cur ^ 1] + t * 16;
                __builtin_amdgcn_global_load_lds(GLB(kp + kso0), LDS(kd), 16, 0, 0);
                __builtin_amdgcn_global_load_lds(GLB(kp + kso1), LDS(kd + 4096), 16, 0, 0);
                __builtin_amdgcn_global_load_lds(GLB(vp + vso0), LDS(vd), 16, 0, 0);
                __builtin_amdgcn_global_load_lds(GLB(vp + vso1), LDS(vd + 4096), 16, 0, 0);
                kp += 8192; vp += 128;
            }

            const char* kb = (const char*)Ks[cur];
            const char* vb = (const char*)Vs[cur];

            // S^T = K Q^T: D[m=key][n=query]; lane: query=lrow, key=nb*16+quad*4+r
            f32x4 sa[4] = {};
            __builtin_amdgcn_s_setprio(1);
            #pragma unroll
            for (int ks = 0; ks < 2; ++ks) {
                const int ro = rk0 ^ (ks * 64);
                #pragma unroll
                for (int nb = 0; nb < 4; ++nb) {
                    bf16x8 kf = *(const bf16x8*)(kb + (nb * 16 + lrow) * 128 + ro);
                    sa[nb] = __builtin_amdgcn_mfma_f32_16x16x32_bf16(kf, qf[ks], sa[nb], 0, 0, 0);
                }
            }
            __builtin_amdgcn_s_setprio(0);

            if (kt == qtile) {  // diagonal tile: causal mask
                int q = qbase + w * 16 + lrow;
                #pragma unroll
                for (int nb = 0; nb < 4; ++nb) {
                    int key = kt * 64 + nb * 16 + quad * 4;
                    #pragma unroll
                    for (int r = 0; r < 4; ++r)
                        if (key + r > q) sa[nb][r] = -3.0e4f;
                }
            }

            // online softmax (exp2 domain) with defer-max (T13):
            // skip rescale while tile max stays within 2^8 of running max
            float p[4][4];
            {
                float rm = fmaxf(fmaxf(sa[0][0], sa[0][1]), fmaxf(sa[0][2], sa[0][3]));
                #pragma unroll
                for (int nb = 1; nb < 4; ++nb)
                    rm = fmaxf(rm, fmaxf(fmaxf(sa[nb][0], sa[nb][1]),
                                         fmaxf(sa[nb][2], sa[nb][3])));
                rm = fmaxf(rm, __shfl_xor(rm, 16));
                rm = fmaxf(rm, __shfl_xor(rm, 32));
                const bool heavy = !__all(rm <= m_i + 8.0f);
                float mnew = heavy ? fmaxf(m_i, rm) : m_i;
                float rs = 0.0f;
                #pragma unroll
                for (int nb = 0; nb < 4; ++nb)
                    #pragma unroll
                    for (int r = 0; r < 4; ++r) {
                        float e = exp2f(sa[nb][r] - mnew);
                        p[nb][r] = e;
                        rs += e;
                    }
                rs += __shfl_xor(rs, 16);
                rs += __shfl_xor(rs, 32);
                if (heavy) {
                    float al = exp2f(m_i - mnew);
                    m_i = mnew;
                    l_i = l_i * al + rs;
                    #pragma unroll
                    for (int nb = 0; nb < 4; ++nb)
                        #pragma unroll
                        for (int r = 0; r < 4; ++r)
                            o_acc[nb][r] *= al;
                } else {
                    l_i += rs;
                }
            }

            // mid-tile barrier: all waves done reading Ks[cur] (QK^T) before
            // P overwrites it. lgkmcnt only — prefetch vmcnt stays in flight.
            asm volatile("s_waitcnt lgkmcnt(0)" ::: "memory");
            __builtin_amdgcn_s_barrier();
            asm volatile("" ::: "memory");

            // P -> dead Ks[cur], per-wave 2KB quarter, [query][key] swizzled
            char* pw = (char*)Ks[cur] + w * 2048 + lrow * 128;
            #pragma unroll
            for (int nb = 0; nb < 4; ++nb) {
                bf16x4 pk;
                #pragma unroll
                for (int r = 0; r < 4; ++r)
                    pk[r] = (bf16)p[nb][r];
                *(bf16x4*)(pw + ((nb * 32 + quad * 8) ^ swz)) = pk;
            }
            asm volatile("s_waitcnt lgkmcnt(0)" ::: "memory");

            // O^T += V^T P^T: A=V^T[hd][key], B=P[query][key]
            __builtin_amdgcn_s_setprio(1);
            #pragma unroll
            for (int ks = 0; ks < 2; ++ks) {
                const int ro = rk0 ^ (ks * 64);
                bf16x8 pf = *(const bf16x8*)(pw + ro);
                #pragma unroll
                for (int nb = 0; nb < 4; ++nb) {
                    bf16x8 vf = *(const bf16x8*)(vb + (nb * 16 + lrow) * 128 + ro);
                    o_acc[nb] = __builtin_amdgcn_mfma_f32_16x16x32_bf16(vf, pf, o_acc[nb], 0, 0, 0);
                }
            }
            __builtin_amdgcn_s_setprio(0);

            // end-of-tile barrier: prefetch landed (vmcnt) and all LDS reads
            // of [cur] done (lgkmcnt) — [cur] becomes next prefetch target.
            asm volatile("s_waitcnt vmcnt(0) lgkmcnt(0)" ::: "memory");
            __builtin_amdgcn_s_barrier();
            asm volatile("" ::: "memory");
            cur ^= 1;
        }

        // epilogue: O^T regs -> O[b,s,d]; lane: s=query fixed, 4 consecutive hd
        {
            float inv = 1.0f / l_i;
            int s = qbase + w * 16 + lrow;
            #pragma unroll
            for (int nb = 0; nb < 4; ++nb) {
                bf16x4 pk;
                #pragma unroll
                for (int r = 0; r < 4; ++r)
                    pk[r] = (bf16)(o_acc[nb][r] * inv);
                *(bf16x4*)(O + ((size_t)b * S_ + s) * D_ + h * 64 + nb * 16 + quad * 4) = pk;
            }
        }
        // loop ended with a full barrier; epilogue touches no LDS -> next
        // half's prologue staging is race-free
    }
}

// ---------------- pass 3: output projection GEMM (fp32 out) ----------------
__global__ __launch_bounds__(256) void proj_gemm(
    const bf16* __restrict__ A, const bf16* __restrict__ WpT,
    const float* __restrict__ bp, float* __restrict__ out)
{
    __shared__ bf16 As[128 * 32];
    __shared__ bf16 Bs[128 * 32];

    const int t = threadIdx.x;
    const int lid = t & 63, w = t >> 6;
    const int wm = w & 1, wn = w >> 1;
    const int lrow = lid & 15, quad = lid >> 4;
    const int m0 = blockIdx.y * 128, n0 = blockIdx.x * 128;

    const bf16* Ag = A   + (size_t)m0 * D_;
    const bf16* Bg = WpT + (size_t)n0 * D_;

    const int row0 = t >> 2, k80 = (t & 3) << 3;
    const int row1 = (t + 256) >> 2;

    f32x4 acc[4][4] = {};

    for (int k0 = 0; k0 < D_; k0 += 32) {
        __syncthreads();
        __builtin_amdgcn_global_load_lds(GLB(Ag + (size_t)row0 * D_ + k0 + k80),
                                         LDS(As + t * 8), 16, 0, 0);
        __builtin_amdgcn_global_load_lds(GLB(Bg + (size_t)row0 * D_ + k0 + k80),
                                         LDS(Bs + t * 8), 16, 0, 0);
        __builtin_amdgcn_global_load_lds(GLB(Ag + (size_t)row1 * D_ + k0 + k80),
                                         LDS(As + t * 8 + 2048), 16, 0, 0);
        __builtin_amdgcn_global_load_lds(GLB(Bg + (size_t)row1 * D_ + k0 + k80),
                                         LDS(Bs + t * 8 + 2048), 16, 0, 0);
        __syncthreads();
        bf16x8 a[4], b[4];
        #pragma unroll
        for (int mb = 0; mb < 4; ++mb)
            a[mb] = *(const bf16x8*)(As + (wm * 64 + mb * 16 + lrow) * 32 + quad * 8);
        #pragma unroll
        for (int nb = 0; nb < 4; ++nb)
            b[nb] = *(const bf16x8*)(Bs + (wn * 64 + nb * 16 + lrow) * 32 + quad * 8);
        #pragma unroll
        for (int mb = 0; mb < 4; ++mb)
            #pragma unroll
            for (int nb = 0; nb < 4; ++nb)
                acc[mb][nb] = __builtin_amdgcn_mfma_f32_16x16x32_bf16(a[mb], b[nb], acc[mb][nb], 0, 0, 0);
    }

    #pragma unroll
    for (int mb = 0; mb < 4; ++mb) {
        #pragma unroll
        for (int nb = 0; nb < 4; ++nb) {
            int gn = n0 + wn * 64 + nb * 16 + lrow;
            float bsv = bp[gn];
            #pragma unroll
            for (int r = 0; r < 4; ++r) {
                int gm = m0 + wm * 64 + mb * 16 + quad * 4 + r;
                out[(size_t)gm * D_ + gn] = acc[mb][nb][r] + bsv;
            }
        }
    }
}

// ---------------- launch ----------------
extern "C" void kernel_launch(void* const* d_in, const int* in_sizes, int n_in,
                              void* d_out, int out_size, void* d_ws, size_t ws_size,
                              hipStream_t stream)
{
    const float* x  = (const float*)d_in[0];
    const float* Wq = (const float*)d_in[1];
    const float* bq = (const float*)d_in[2];
    const float* Wk = (const float*)d_in[3];
    const float* bk = (const float*)d_in[4];
    const float* Wv = (const float*)d_in[5];
    const float* bv = (const float*)d_in[6];
    const float* Wp = (const float*)d_in[7];
    const float* bp = (const float*)d_in[8];

    bf16* ws = (bf16*)d_ws;
    const size_t WSZ = (size_t)D_ * D_;        // 1,048,576 elems
    const size_t BIG = (size_t)B_ * S_ * D_;   // 8,388,608 elems
    bf16* WqT = ws;
    bf16* WkT = WqT + WSZ;
    bf16* WvT = WkT + WSZ;
    bf16* WpT = WvT + WSZ;
    bf16* Qb  = WpT + WSZ;
    bf16* Kb  = Qb + BIG;
    bf16* Vb  = Kb + BIG;    // V^T layout [b,h,hd,s]
    bf16* Ab  = Vb + BIG;    // X(bf16) during qkv, then attention output

    transpose_cvt<<<dim3(32, 32, 4), 256, 0, stream>>>(
        Wq, Wk, Wv, Wp, WqT, WkT, WvT, WpT);

    cvt_x<<<dim3(4096), 256, 0, stream>>>(x, Ab);

    qkv_gemm<<<dim3(8, 64, 3), 256, 0, stream>>>(
        Ab, WqT, WkT, WvT, bq, bk, bv, Qb, Kb, Vb);

    attn_fwd<<<dim3(16, 64), 256, 0, stream>>>(Qb, Kb, Vb, Ab);

    proj_gemm<<<dim3(8, 64), 256, 0, stream>>>(Ab, WpT, bp, (float*)d_out);
}

// Round 3
// 273.994 us; speedup vs baseline: 1.1258x; 1.1258x over previous
//
#include <hip/hip_runtime.h>

typedef __bf16 bf16;
typedef __attribute__((ext_vector_type(4))) __bf16 bf16x4;
typedef __attribute__((ext_vector_type(8))) __bf16 bf16x8;
typedef __attribute__((ext_vector_type(4))) float f32x4;
typedef __attribute__((ext_vector_type(4))) unsigned int u32x4;

#define B_ 4
#define S_ 2048
#define D_ 1024
#define H_ 16
#define HD_ 64

#define GLB(p) ((const __attribute__((address_space(1))) void*)(p))
#define LDS(p) ((__attribute__((address_space(3))) void*)(p))

// ---------------- pass 0a: weight transpose+convert (K,N)fp32 -> (N,K)bf16 --
__global__ __launch_bounds__(256) void transpose_cvt(
    const float* __restrict__ W0, const float* __restrict__ W1,
    const float* __restrict__ W2, const float* __restrict__ W3,
    bf16* __restrict__ T0, bf16* __restrict__ T1,
    bf16* __restrict__ T2, bf16* __restrict__ T3)
{
    __shared__ float tile[32][33];
    int z = blockIdx.z;
    const float* W = (z == 0) ? W0 : (z == 1) ? W1 : (z == 2) ? W2 : W3;
    bf16*        T = (z == 0) ? T0 : (z == 1) ? T1 : (z == 2) ? T2 : T3;
    int bx = blockIdx.x * 32, by = blockIdx.y * 32;
    int tx = threadIdx.x & 31, ty = threadIdx.x >> 5;
    #pragma unroll
    for (int j = 0; j < 32; j += 8)
        tile[ty + j][tx] = W[(size_t)(by + ty + j) * D_ + bx + tx];
    __syncthreads();
    #pragma unroll
    for (int j = 0; j < 32; j += 8)
        T[(size_t)(bx + ty + j) * D_ + by + tx] = (bf16)tile[tx][ty + j];
}

// ---------------- pass 0b: X fp32 -> bf16 ----------------
__global__ __launch_bounds__(256) void cvt_x(
    const float* __restrict__ X, bf16* __restrict__ Xb)
{
    size_t i = ((size_t)blockIdx.x * 256 + threadIdx.x) * 8;
    f32x4 a = *(const f32x4*)(X + i);
    f32x4 b = *(const f32x4*)(X + i + 4);
    bf16x8 v;
    #pragma unroll
    for (int j = 0; j < 4; ++j) { v[j] = (bf16)a[j]; v[4 + j] = (bf16)b[j]; }
    *(bf16x8*)(Xb + i) = v;
}

// ---------------- pass 1: fused QKV projection GEMM ----------------
// C(8192x1024) = Xb(bf16) @ W, WT(N,K) bf16 in ws. 128x128 tile, BK=32.
// Staging via global_load_lds width=16. Epilogue: Q -> (b,h,s,hd) pre-scaled
// by log2(e)/8; K -> (b,h,s,hd); V -> (b,h,hd,s) transposed (packed stores).
__global__ __launch_bounds__(256) void qkv_gemm(
    const bf16* __restrict__ Xb,
    const bf16* __restrict__ WqT, const bf16* __restrict__ WkT, const bf16* __restrict__ WvT,
    const float* __restrict__ bq, const float* __restrict__ bk, const float* __restrict__ bv,
    bf16* __restrict__ Qo, bf16* __restrict__ Ko, bf16* __restrict__ Vo)
{
    const int z = blockIdx.z;
    const bf16*  WT   = (z == 0) ? WqT : (z == 1) ? WkT : WvT;
    const float* bias = (z == 0) ? bq  : (z == 1) ? bk  : bv;
    bf16*        out  = (z == 0) ? Qo  : (z == 1) ? Ko  : Vo;
    const float scale = (z == 0) ? 0.18033688011112042f : 1.0f;

    __shared__ bf16 As[128 * 32];
    __shared__ bf16 Bs[128 * 32];

    const int t = threadIdx.x;
    const int lid = t & 63, w = t >> 6;
    const int wm = w & 1, wn = w >> 1;
    const int lrow = lid & 15, quad = lid >> 4;
    const int m0 = blockIdx.y * 128, n0 = blockIdx.x * 128;

    const bf16* Ag = Xb + (size_t)m0 * D_;
    const bf16* Bg = WT + (size_t)n0 * D_;

    const int row0 = t >> 2, k80 = (t & 3) << 3;
    const int row1 = (t + 256) >> 2;

    f32x4 acc[4][4] = {};

    for (int k0 = 0; k0 < D_; k0 += 32) {
        __syncthreads();
        __builtin_amdgcn_global_load_lds(GLB(Ag + (size_t)row0 * D_ + k0 + k80),
                                         LDS(As + t * 8), 16, 0, 0);
        __builtin_amdgcn_global_load_lds(GLB(Bg + (size_t)row0 * D_ + k0 + k80),
                                         LDS(Bs + t * 8), 16, 0, 0);
        __builtin_amdgcn_global_load_lds(GLB(Ag + (size_t)row1 * D_ + k0 + k80),
                                         LDS(As + t * 8 + 2048), 16, 0, 0);
        __builtin_amdgcn_global_load_lds(GLB(Bg + (size_t)row1 * D_ + k0 + k80),
                                         LDS(Bs + t * 8 + 2048), 16, 0, 0);
        __syncthreads();
        bf16x8 a[4], b[4];
        #pragma unroll
        for (int mb = 0; mb < 4; ++mb)
            a[mb] = *(const bf16x8*)(As + (wm * 64 + mb * 16 + lrow) * 32 + quad * 8);
        #pragma unroll
        for (int nb = 0; nb < 4; ++nb)
            b[nb] = *(const bf16x8*)(Bs + (wn * 64 + nb * 16 + lrow) * 32 + quad * 8);
        #pragma unroll
        for (int mb = 0; mb < 4; ++mb)
            #pragma unroll
            for (int nb = 0; nb < 4; ++nb)
                acc[mb][nb] = __builtin_amdgcn_mfma_f32_16x16x32_bf16(a[mb], b[nb], acc[mb][nb], 0, 0, 0);
    }

    #pragma unroll
    for (int mb = 0; mb < 4; ++mb) {
        #pragma unroll
        for (int nb = 0; nb < 4; ++nb) {
            int gn = n0 + wn * 64 + nb * 16 + lrow;
            float bsv = bias[gn];
            int h = gn >> 6, hd = gn & 63;
            int gm0 = m0 + wm * 64 + mb * 16 + quad * 4;
            int bb = gm0 >> 11, s0 = gm0 & 2047;
            if (z == 2) {
                // V^T: [b, h, hd, s] — 4 consecutive s, packed 8B store
                bf16x4 pk;
                #pragma unroll
                for (int r = 0; r < 4; ++r)
                    pk[r] = (bf16)(acc[mb][nb][r] + bsv);
                *(bf16x4*)(out + (((size_t)(bb * H_ + h)) * HD_ + hd) * S_ + s0) = pk;
            } else {
                // Q/K: [b, h, s, hd]
                #pragma unroll
                for (int r = 0; r < 4; ++r) {
                    float v = (acc[mb][nb][r] + bsv) * scale;
                    out[(((size_t)(bb * H_ + h)) * S_ + (s0 + r)) * HD_ + hd] = (bf16)v;
                }
            }
        }
    }
}

// ---------------- pass 2: causal flash attention (S-transposed scheme) -----
// v4: revert to v1's known-good skeleton (sync VGPR staging, 2 __syncthreads
// per tile, NO setprio — m190: setprio hurts barrier-lockstep blocks) and
// graft only clean-mechanism wins:
//  * XOR-swizzled stride-64 LDS, swizzle applied on BOTH write (reg-staged
//    scatter) and read sides — v2 verified conflicts 1.19e7 -> 2.2e6.
//  * softmax VALU diet: P row-sum via constant-ones MFMA (l_acc rides the
//    matrix pipe incl. online rescale; kills 16 adds + 2 shfl per tile),
//    __builtin_amdgcn_exp2f (no libm fixup code), max3-shaped fmax tree.
//  * defer-max (T13) kept from v2/v3 (absmax unchanged across versions).
// LDS = 8K (K) + 8K (V) + 8K (P) = 24576 B.
// 64-query tiles (32 qtiles). Block pair (31-bx, bx) -> constant 33 key-tile
// units/block; grid (16,64) = 1024 blocks = 4/CU.
__global__ __launch_bounds__(256) void attn_fwd(
    const bf16* __restrict__ Q, const bf16* __restrict__ K,
    const bf16* __restrict__ Vt, bf16* __restrict__ O)
{
    __shared__ bf16 Ks[64 * 64];        // [key][hd], 128B rows, XOR-swizzled
    __shared__ bf16 Vs[64 * 64];        // [hd][key], 128B rows, XOR-swizzled
    __shared__ bf16 Ps[4][16 * 64];     // per-wave P [query][key], swizzled

    const int bh = blockIdx.y;
    const int t = threadIdx.x, lid = t & 63, w = t >> 6;
    const int lrow = lid & 15, quad = lid >> 4;
    const int b = bh >> 4, h = bh & 15;

    // read-side swizzle: physical_byte(row, o) = row*128 + (o ^ ((row&7)<<4))
    const int swz = (lrow & 7) << 4;

    // staging thread-constants: thread t owns 16B chunk (t&7) of rows t>>3
    // and t>>3 + 32; LDS destinations swizzled (reg-staged scatter is free).
    const int srow0 = t >> 3, srow1 = srow0 + 32;     // srow1&7 == srow0&7
    const int k8 = (t & 7) << 3;                      // element offset in row
    const int sswz = ((t & 7) << 4) ^ ((srow0 & 7) << 4);
    char* kdst0 = (char*)Ks + srow0 * 128 + sswz;
    char* kdst1 = (char*)Ks + srow1 * 128 + sswz;
    char* vdst0 = (char*)Vs + srow0 * 128 + sswz;
    char* vdst1 = (char*)Vs + srow1 * 128 + sswz;

    // constant ones A-fragment for the MFMA row-sum trick
    bf16x8 onesv;
    #pragma unroll
    for (int j = 0; j < 8; ++j) onesv[j] = (bf16)1.0f;

    #pragma unroll 1
    for (int half = 0; half < 2; ++half) {
        const int qtile = half ? blockIdx.x : (31 - blockIdx.x);
        const int qbase = qtile * 64;

        // Q fragments (B-operand): lane n=query=lrow, k=hd in-lane
        const bf16* Qp = Q + ((size_t)bh * S_ + qbase + w * 16) * HD_;
        bf16x8 qf[2];
        #pragma unroll
        for (int ks = 0; ks < 2; ++ks)
            qf[ks] = *(const bf16x8*)(Qp + lrow * HD_ + ks * 32 + quad * 8);

        f32x4 o_acc[4] = {};              // O^T: [hd-block], col=query
        f32x4 l_acc = {0.0f, 0.0f, 0.0f, 0.0f};  // MFMA-accumulated row-sums
        float m_i = -3.0e4f;

        for (int kt = 0; kt <= qtile; ++kt) {
            const bf16* Kp = K  + ((size_t)bh * S_ + kt * 64) * HD_;
            const bf16* Vp = Vt + ((size_t)bh * HD_) * S_ + kt * 64;
            __syncthreads();
            u32x4 kv0 = *(const u32x4*)(Kp + (size_t)srow0 * HD_ + k8);
            u32x4 kv1 = *(const u32x4*)(Kp + (size_t)srow1 * HD_ + k8);
            u32x4 vv0 = *(const u32x4*)(Vp + (size_t)srow0 * S_ + k8);
            u32x4 vv1 = *(const u32x4*)(Vp + (size_t)srow1 * S_ + k8);
            *(u32x4*)kdst0 = kv0;
            *(u32x4*)kdst1 = kv1;
            *(u32x4*)vdst0 = vv0;
            *(u32x4*)vdst1 = vv1;
            __syncthreads();

            // S^T = K Q^T: D[m=key][n=query]; lane: query=lrow, key=nb*16+quad*4+r
            f32x4 sa[4] = {};
            #pragma unroll
            for (int ks = 0; ks < 2; ++ks) {
                const int ro = ((ks << 6) + (quad << 4)) ^ swz;
                #pragma unroll
                for (int nb = 0; nb < 4; ++nb) {
                    bf16x8 kf = *(const bf16x8*)((const char*)Ks + (nb * 16 + lrow) * 128 + ro);
                    sa[nb] = __builtin_amdgcn_mfma_f32_16x16x32_bf16(kf, qf[ks], sa[nb], 0, 0, 0);
                }
            }

            if (kt == qtile) {  // diagonal tile: causal mask
                int q = qbase + w * 16 + lrow;
                #pragma unroll
                for (int nb = 0; nb < 4; ++nb) {
                    int key = kt * 64 + nb * 16 + quad * 4;
                    #pragma unroll
                    for (int r = 0; r < 4; ++r)
                        if (key + r > q) sa[nb][r] = -3.0e4f;
                }
            }

            // online softmax (exp2 domain), defer-max (T13), raw v_exp_f32,
            // max3-shaped reduce; row-sum handled by the ones-MFMA below.
            float p[4][4];
            {
                float r0 = fmaxf(fmaxf(sa[0][0], sa[0][1]), sa[0][2]);
                float r1 = fmaxf(fmaxf(sa[0][3], sa[1][0]), sa[1][1]);
                float r2 = fmaxf(fmaxf(sa[1][2], sa[1][3]), sa[2][0]);
                float r3 = fmaxf(fmaxf(sa[2][1], sa[2][2]), sa[2][3]);
                float r4 = fmaxf(fmaxf(sa[3][0], sa[3][1]), sa[3][2]);
                float rm = fmaxf(fmaxf(fmaxf(r0, r1), r2),
                                 fmaxf(fmaxf(r3, r4), sa[3][3]));
                rm = fmaxf(rm, __shfl_xor(rm, 16));
                rm = fmaxf(rm, __shfl_xor(rm, 32));
                const bool heavy = !__all(rm <= m_i + 8.0f);
                if (heavy) {
                    float mnew = fmaxf(m_i, rm);
                    float al = __builtin_amdgcn_exp2f(m_i - mnew);
                    m_i = mnew;
                    #pragma unroll
                    for (int nb = 0; nb < 4; ++nb)
                        #pragma unroll
                        for (int r = 0; r < 4; ++r)
                            o_acc[nb][r] *= al;
                    #pragma unroll
                    for (int r = 0; r < 4; ++r)
                        l_acc[r] *= al;
                }
                #pragma unroll
                for (int nb = 0; nb < 4; ++nb)
                    #pragma unroll
                    for (int r = 0; r < 4; ++r)
                        p[nb][r] = __builtin_amdgcn_exp2f(sa[nb][r] - m_i);
            }

            // P -> LDS [query][key] swizzled, packed b64 (keys quad*4..+3)
            char* pw = (char*)Ps[w] + lrow * 128;
            #pragma unroll
            for (int nb = 0; nb < 4; ++nb) {
                bf16x4 pk;
                #pragma unroll
                for (int r = 0; r < 4; ++r)
                    pk[r] = (bf16)p[nb][r];
                *(bf16x4*)(pw + ((nb * 32 + quad * 8) ^ swz)) = pk;
            }
            asm volatile("s_waitcnt lgkmcnt(0)" ::: "memory");

            // O^T += V^T P^T: A=V^T[hd][key], B=P[query][key];
            // l_acc += ones * P^T  (row-sum on the matrix pipe)
            #pragma unroll
            for (int ks = 0; ks < 2; ++ks) {
                const int ro = ((ks << 6) + (quad << 4)) ^ swz;
                bf16x8 pf = *(const bf16x8*)(pw + ro);
                #pragma unroll
                for (int nb = 0; nb < 4; ++nb) {
                    bf16x8 vf = *(const bf16x8*)((const char*)Vs + (nb * 16 + lrow) * 128 + ro);
                    o_acc[nb] = __builtin_amdgcn_mfma_f32_16x16x32_bf16(vf, pf, o_acc[nb], 0, 0, 0);
                }
                l_acc = __builtin_amdgcn_mfma_f32_16x16x32_bf16(onesv, pf, l_acc, 0, 0, 0);
            }
        }

        // epilogue: O^T regs -> O[b,s,d]; lane: s=query fixed, 4 consecutive hd
        {
            float inv = 1.0f / l_acc[0];   // all 4 rows identical = row-sum
            int s = qbase + w * 16 + lrow;
            #pragma unroll
            for (int nb = 0; nb < 4; ++nb) {
                bf16x4 pk;
                #pragma unroll
                for (int r = 0; r < 4; ++r)
                    pk[r] = (bf16)(o_acc[nb][r] * inv);
                *(bf16x4*)(O + ((size_t)b * S_ + s) * D_ + h * 64 + nb * 16 + quad * 4) = pk;
            }
        }
        __syncthreads();   // protect LDS before next half re-stages
    }
}

// ---------------- pass 3: output projection GEMM (fp32 out) ----------------
__global__ __launch_bounds__(256) void proj_gemm(
    const bf16* __restrict__ A, const bf16* __restrict__ WpT,
    const float* __restrict__ bp, float* __restrict__ out)
{
    __shared__ bf16 As[128 * 32];
    __shared__ bf16 Bs[128 * 32];

    const int t = threadIdx.x;
    const int lid = t & 63, w = t >> 6;
    const int wm = w & 1, wn = w >> 1;
    const int lrow = lid & 15, quad = lid >> 4;
    const int m0 = blockIdx.y * 128, n0 = blockIdx.x * 128;

    const bf16* Ag = A   + (size_t)m0 * D_;
    const bf16* Bg = WpT + (size_t)n0 * D_;

    const int row0 = t >> 2, k80 = (t & 3) << 3;
    const int row1 = (t + 256) >> 2;

    f32x4 acc[4][4] = {};

    for (int k0 = 0; k0 < D_; k0 += 32) {
        __syncthreads();
        __builtin_amdgcn_global_load_lds(GLB(Ag + (size_t)row0 * D_ + k0 + k80),
                                         LDS(As + t * 8), 16, 0, 0);
        __builtin_amdgcn_global_load_lds(GLB(Bg + (size_t)row0 * D_ + k0 + k80),
                                         LDS(Bs + t * 8), 16, 0, 0);
        __builtin_amdgcn_global_load_lds(GLB(Ag + (size_t)row1 * D_ + k0 + k80),
                                         LDS(As + t * 8 + 2048), 16, 0, 0);
        __builtin_amdgcn_global_load_lds(GLB(Bg + (size_t)row1 * D_ + k0 + k80),
                                         LDS(Bs + t * 8 + 2048), 16, 0, 0);
        __syncthreads();
        bf16x8 a[4], b[4];
        #pragma unroll
        for (int mb = 0; mb < 4; ++mb)
            a[mb] = *(const bf16x8*)(As + (wm * 64 + mb * 16 + lrow) * 32 + quad * 8);
        #pragma unroll
        for (int nb = 0; nb < 4; ++nb)
            b[nb] = *(const bf16x8*)(Bs + (wn * 64 + nb * 16 + lrow) * 32 + quad * 8);
        #pragma unroll
        for (int mb = 0; mb < 4; ++mb)
            #pragma unroll
            for (int nb = 0; nb < 4; ++nb)
                acc[mb][nb] = __builtin_amdgcn_mfma_f32_16x16x32_bf16(a[mb], b[nb], acc[mb][nb], 0, 0, 0);
    }

    #pragma unroll
    for (int mb = 0; mb < 4; ++mb) {
        #pragma unroll
        for (int nb = 0; nb < 4; ++nb) {
            int gn = n0 + wn * 64 + nb * 16 + lrow;
            float bsv = bp[gn];
            #pragma unroll
            for (int r = 0; r < 4; ++r) {
                int gm = m0 + wm * 64 + mb * 16 + quad * 4 + r;
                out[(size_t)gm * D_ + gn] = acc[mb][nb][r] + bsv;
            }
        }
    }
}

// ---------------- launch ----------------
extern "C" void kernel_launch(void* const* d_in, const int* in_sizes, int n_in,
                              void* d_out, int out_size, void* d_ws, size_t ws_size,
                              hipStream_t stream)
{
    const float* x  = (const float*)d_in[0];
    const float* Wq = (const float*)d_in[1];
    const float* bq = (const float*)d_in[2];
    const float* Wk = (const float*)d_in[3];
    const float* bk = (const float*)d_in[4];
    const float* Wv = (const float*)d_in[5];
    const float* bv = (const float*)d_in[6];
    const float* Wp = (const float*)d_in[7];
    const float* bp = (const float*)d_in[8];

    bf16* ws = (bf16*)d_ws;
    const size_t WSZ = (size_t)D_ * D_;        // 1,048,576 elems
    const size_t BIG = (size_t)B_ * S_ * D_;   // 8,388,608 elems
    bf16* WqT = ws;
    bf16* WkT = WqT + WSZ;
    bf16* WvT = WkT + WSZ;
    bf16* WpT = WvT + WSZ;
    bf16* Qb  = WpT + WSZ;
    bf16* Kb  = Qb + BIG;
    bf16* Vb  = Kb + BIG;    // V^T layout [b,h,hd,s]
    bf16* Ab  = Vb + BIG;    // X(bf16) during qkv, then attention output

    transpose_cvt<<<dim3(32, 32, 4), 256, 0, stream>>>(
        Wq, Wk, Wv, Wp, WqT, WkT, WvT, WpT);

    cvt_x<<<dim3(4096), 256, 0, stream>>>(x, Ab);

    qkv_gemm<<<dim3(8, 64, 3), 256, 0, stream>>>(
        Ab, WqT, WkT, WvT, bq, bk, bv, Qb, Kb, Vb);

    attn_fwd<<<dim3(16, 64), 256, 0, stream>>>(Qb, Kb, Vb, Ab);

    proj_gemm<<<dim3(8, 64), 256, 0, stream>>>(Ab, WpT, bp, (float*)d_out);
}